// Round 8
// baseline (98.161 us; speedup 1.0000x reference)
//
#include <hip/hip_runtime.h>
#include <stdint.h>

#define HIDDEN 2048
#define EXPERTS 64
#define T_TOTAL 8192

// ================= GEMM: split-K, global_load_lds staged, 8x8 micro-tile =================
// Block: 128 thr (2 waves), BM=128 rows x 64 experts. Thread: rg=t>>3 (0..15) -> rows
// rg*8..+7, eg=t&7 -> experts eg*8..+7. Per q-step: 8 A b128 + 8 W b128 feed 256 fma
// (16 fma/LDS-read).
// A tile XOR-swizzle keyed on (row>>3)&7  == rg for every row this thread reads
// (R7 bug: (row>>2)&7 varied across the 8 rows of the micro-tile -> wrong columns).
// Applied on BOTH sides: pre-swizzled gload source + swizzled ds_read (rule 21).
// Read banks: 8 distinct rg/wave -> 8 distinct q^(rg&7) -> groups {0,4..28}, conflict-free.
// W tile linear [k][e]: 2-way aliasing = free.
#define BM 128
#define BK 32

#define GLOAD16(g, l) __builtin_amdgcn_global_load_lds(                        \
        (const __attribute__((address_space(1))) unsigned int*)(g),            \
        (__attribute__((address_space(3))) unsigned int*)(l), 16, 0, 0)
#define FENCE() asm volatile("" ::: "memory")

template <int KS>
__global__ __launch_bounds__(128, 1) void snn_gemm_sk(
        const float* __restrict__ A, const float* __restrict__ W,
        float* __restrict__ P, int* __restrict__ flags) {
    __shared__ float As[2][BM * BK];        // 2 x 16 KB
    __shared__ float Ws[2][BK * EXPERTS];   // 2 x 8 KB

    const int t    = threadIdx.x;           // 0..127
    const int lane = t & 63;
    const int wv   = t >> 6;                // 0..1
    const int rg   = t >> 3;                // 0..15 : rows rg*8..rg*8+7
    const int eg   = t & 7;                 // 0..7  : experts eg*8..eg*8+7
    const long row0 = (long)blockIdx.x * BM;
    const int  k0   = blockIdx.y * KS;
    float* Pout = P + (long)blockIdx.y * ((long)T_TOTAL * EXPERTS);

    // replaces hipMemsetAsync: scan runs after this kernel completes (stream order)
    if (blockIdx.x == 0 && blockIdx.y == 0) flags[t] = 0;   // 128 ints

    // ---- staging geometry ----
    // A: 8 rounds of 128 lanes x 16B. Round p, LDS word = p*512 + wv*256 + lane*4:
    //   row = p*16 + wv*8 + (lane>>3), colblk = lane&7. Stored value must be
    //   A[row][colblk ^ ((row>>3)&7)] -> pre-swizzle the GLOBAL source column.
    const int l3 = lane >> 3, l7 = lane & 7;
    const float* aSrc[8];
#pragma unroll
    for (int p = 0; p < 8; ++p) {
        const int row = p * 16 + wv * 8 + l3;
        const int cb  = l7 ^ ((row >> 3) & 7);     // <- fixed: >>3, == rg of the reader
        aSrc[p] = &A[(row0 + row) * HIDDEN + k0 + cb * 4];
    }
    // W: 4 rounds. Round p, LDS word = p*512 + wv*256 + lane*4:
    //   k = p*8 + wv*4 + (lane>>4), e4 = lane&15. Linear both sides.
    const float* wSrc[4];
#pragma unroll
    for (int p = 0; p < 4; ++p)
        wSrc[p] = &W[(long)(k0 + p * 8 + wv * 4 + (lane >> 4)) * EXPERTS + (lane & 15) * 4];

    auto stage = [&](int tile, int buf) {
        const int  aoff = tile * BK;
        const long woff = (long)tile * BK * EXPERTS;
#pragma unroll
        for (int p = 0; p < 8; ++p)
            GLOAD16(aSrc[p] + aoff, &As[buf][p * 512 + wv * 256]);   // +lane*16B by HW
#pragma unroll
        for (int p = 0; p < 4; ++p)
            GLOAD16(wSrc[p] + woff, &Ws[buf][p * 512 + wv * 256]);
    };

    float acc[8][8];
#pragma unroll
    for (int i = 0; i < 8; ++i)
#pragma unroll
        for (int j = 0; j < 8; ++j) acc[i][j] = 0.0f;

    stage(0, 0);

    constexpr int NTILE = KS / BK;
    int buf = 0;
    for (int tile = 0; tile < NTILE; ++tile) {
        if (tile + 1 < NTILE) {
            stage(tile + 1, buf ^ 1);
            asm volatile("s_waitcnt vmcnt(12)" ::: "memory");   // oldest 12 (current tile) landed
        } else {
            asm volatile("s_waitcnt vmcnt(0)" ::: "memory");
        }
        __builtin_amdgcn_s_barrier();
        FENCE();

        const float* ab = &As[buf][0];
        const float* wb = &Ws[buf][0];
        const int swz = rg & 7;   // == (row>>3)&7 for every row rg*8+i, i<8
#pragma unroll
        for (int q = 0; q < BK / 4; ++q) {
            const int qs = (q ^ swz) * 4;   // LDS slot holding true cols q*4..q*4+3
            float4 a4[8];
#pragma unroll
            for (int i = 0; i < 8; ++i)
                a4[i] = *reinterpret_cast<const float4*>(&ab[(rg * 8 + i) * BK + qs]);
#pragma unroll
            for (int ki = 0; ki < 4; ++ki) {   // k ascending: q outer, ki inner
                const float4 w0 = *reinterpret_cast<const float4*>(&wb[(q * 4 + ki) * EXPERTS + eg * 8]);
                const float4 w1 = *reinterpret_cast<const float4*>(&wb[(q * 4 + ki) * EXPERTS + eg * 8 + 4]);
#pragma unroll
                for (int i = 0; i < 8; ++i) {
                    const float av = (&a4[i].x)[ki];
                    acc[i][0] = fmaf(av, w0.x, acc[i][0]);
                    acc[i][1] = fmaf(av, w0.y, acc[i][1]);
                    acc[i][2] = fmaf(av, w0.z, acc[i][2]);
                    acc[i][3] = fmaf(av, w0.w, acc[i][3]);
                    acc[i][4] = fmaf(av, w1.x, acc[i][4]);
                    acc[i][5] = fmaf(av, w1.y, acc[i][5]);
                    acc[i][6] = fmaf(av, w1.z, acc[i][6]);
                    acc[i][7] = fmaf(av, w1.w, acc[i][7]);
                }
            }
        }
        FENCE();
        __builtin_amdgcn_s_barrier();   // all waves done with buf before restage
        buf ^= 1;
    }

#pragma unroll
    for (int i = 0; i < 8; ++i) {
        float* base = &Pout[(row0 + rg * 8 + i) * EXPERTS + eg * 8];
        *reinterpret_cast<float4*>(base)     = make_float4(acc[i][0], acc[i][1], acc[i][2], acc[i][3]);
        *reinterpret_cast<float4*>(base + 4) = make_float4(acc[i][4], acc[i][5], acc[i][6], acc[i][7]);
    }
}

// ---- fixed-order split-K combine: cur = (((p0+p1)+p2)+...) ----
__global__ __launch_bounds__(256) void snn_combine(const float* __restrict__ P,
                                                   float* __restrict__ cur, int nsplit) {
    const long i = (long)blockIdx.x * 256 + threadIdx.x;   // float4 index
    const float4* p = reinterpret_cast<const float4*>(P);
    float4 s = p[i];
    for (int k = 1; k < nsplit; ++k) {
        const float4 v = p[i + (long)k * (T_TOTAL * EXPERTS / 4)];
        s.x += v.x; s.y += v.y; s.z += v.z; s.w += v.w;
    }
    reinterpret_cast<float4*>(cur)[i] = s;
}

// ========= Scan (WFR, 32 chunks x 256 steps) + FUSED routing softmax =========
// Block: 256 thr. Wave 0 runs the sequential LIF scan (lane = expert), writing the
// pre-reset membrane trajectory to LDS. After a barrier, all 4 waves compute the
// routing softmax (64 rows each) and write d_out directly. No smp global round-trip.
#define NCHUNK 32
#define CSTEPS (T_TOTAL / NCHUNK)   // 256
#define KITER  4
#define PF     32

__global__ __launch_bounds__(256) void snn_scan_wfr(const float* __restrict__ cur,
                                                    float* __restrict__ out,
                                                    float* __restrict__ states,
                                                    int* __restrict__ flags) {
#pragma clang fp contract(off)
    __shared__ float smp[CSTEPS * EXPERTS];   // 64 KB
    const int tid = threadIdx.x;
    const int w   = blockIdx.x;

    if (tid < 64) {
        const int e = tid;
        const float* cbase = cur + (long)w * CSTEPS * EXPERTS + e;

        for (int k = 1; k <= KITER; ++k) {
            float mp = 0.0f, refr = 0.0f;
            if (w > 0 && k > 1) {
                const int s = (k - 2) * NCHUNK + (w - 1);
                if (e == 0) {
                    while (__hip_atomic_load(&flags[s], __ATOMIC_ACQUIRE, __HIP_MEMORY_SCOPE_AGENT) == 0)
                        __builtin_amdgcn_s_sleep(8);
                }
                __threadfence();
                mp   = __hip_atomic_load(&states[s * 2 * EXPERTS + e], __ATOMIC_RELAXED, __HIP_MEMORY_SCOPE_AGENT);
                refr = __hip_atomic_load(&states[s * 2 * EXPERTS + EXPERTS + e], __ATOMIC_RELAXED, __HIP_MEMORY_SCOPE_AGENT);
            }

            float ca[PF], cb[PF];
#pragma unroll
            for (int j = 0; j < PF; ++j) ca[j] = cbase[j * EXPERTS] * 0.1f;

            for (int t0 = 0; t0 < CSTEPS; t0 += 2 * PF) {
#pragma unroll
                for (int j = 0; j < PF; ++j) cb[j] = cbase[(t0 + PF + j) * EXPERTS] * 0.1f;
#pragma unroll
                for (int j = 0; j < PF; ++j) {
                    const float term   = (refr <= 0.0f) ? ca[j] : 0.0f;
                    const float mp_pre = mp * 0.9f + term;
                    smp[(t0 + j) * EXPERTS + e] = mp_pre;
                    const bool spike = mp_pre > 1.0f;
                    mp = spike ? 0.0f : mp_pre;
                    const float rdec = fmaxf(refr - 0.1f, 0.0f);
                    refr = spike ? 1.0f : rdec;
                }
                if (t0 + 2 * PF < CSTEPS) {
#pragma unroll
                    for (int j = 0; j < PF; ++j) ca[j] = cbase[(t0 + 2 * PF + j) * EXPERTS] * 0.1f;
                }
#pragma unroll
                for (int j = 0; j < PF; ++j) {
                    const float term   = (refr <= 0.0f) ? cb[j] : 0.0f;
                    const float mp_pre = mp * 0.9f + term;
                    smp[(t0 + PF + j) * EXPERTS + e] = mp_pre;
                    const bool spike = mp_pre > 1.0f;
                    mp = spike ? 0.0f : mp_pre;
                    const float rdec = fmaxf(refr - 0.1f, 0.0f);
                    refr = spike ? 1.0f : rdec;
                }
            }

            if (k < KITER && w < NCHUNK - 1) {
                const int s2 = (k - 1) * NCHUNK + w;
                __hip_atomic_store(&states[s2 * 2 * EXPERTS + e], mp, __ATOMIC_RELAXED, __HIP_MEMORY_SCOPE_AGENT);
                __hip_atomic_store(&states[s2 * 2 * EXPERTS + EXPERTS + e], refr, __ATOMIC_RELAXED, __HIP_MEMORY_SCOPE_AGENT);
                __threadfence();
                if (e == 0)
                    __hip_atomic_store(&flags[s2], 1, __ATOMIC_RELEASE, __HIP_MEMORY_SCOPE_AGENT);
            }
        }
    }
    __syncthreads();

    // ---- fused routing softmax: wave wvid handles rows wvid*64 .. +63 ----
    const int lane = tid & 63;
    const int wvid = tid >> 6;
    const float em1 = expf(-1.0f);
#pragma unroll 4
    for (int r = wvid * 64; r < wvid * 64 + 64; ++r) {
        const float v = smp[r * EXPERTS + lane];
        const bool spike = v > 1.0f;
        const unsigned long long ball = __ballot(spike);
        float res;
        if (ball != 0ull) {
            const int n = __popcll(ball);
            const float denom = (float)n + (float)(EXPERTS - n) * em1;
            res = spike ? (1.0f / denom) : (em1 / denom);
        } else {
            float m = v;
#pragma unroll
            for (int off = 32; off >= 1; off >>= 1)
                m = fmaxf(m, __shfl_xor(m, off, 64));
            const float p = expf(v - m);
            float s = p;
#pragma unroll
            for (int off = 32; off >= 1; off >>= 1)
                s += __shfl_xor(s, off, 64);
            res = p / s;
        }
        out[((long)w * CSTEPS + r) * EXPERTS + lane] = res;
    }
}

// ---------------------------------------------------------------------------
extern "C" void kernel_launch(void* const* d_in, const int* in_sizes, int n_in,
                              void* d_out, int out_size, void* d_ws, size_t ws_size,
                              hipStream_t stream) {
    const float* hs = (const float*)d_in[0];   // [4,2048,2048] f32
    const float* w  = (const float*)d_in[1];   // [2048,64] f32
    float* out = (float*)d_out;                // [4,2048,64] f32

    char*  ws     = (char*)d_ws;
    int*   flags  = (int*)ws;                          // 128 ints (zeroed by gemm blk 0,0)
    float* states = (float*)(ws + 4096);               // 64 KB
    float* cur    = (float*)(ws + (1u << 20));         // 2 MB @ 1 MB
    float* part   = (float*)(ws + (4u << 20));         // up to 8 x 2 MB @ 4 MB

    const size_t slab = (size_t)T_TOTAL * EXPERTS * sizeof(float);   // 2 MB

    if (ws_size >= (4u << 20) + 8 * slab) {
        snn_gemm_sk<HIDDEN / 8><<<dim3(T_TOTAL / BM, 8), dim3(128), 0, stream>>>(hs, w, part, flags);
        snn_combine<<<dim3(T_TOTAL * EXPERTS / 4 / 256), dim3(256), 0, stream>>>(part, cur, 8);
    } else if (ws_size >= (4u << 20) + 4 * slab) {
        snn_gemm_sk<HIDDEN / 4><<<dim3(T_TOTAL / BM, 4), dim3(128), 0, stream>>>(hs, w, part, flags);
        snn_combine<<<dim3(T_TOTAL * EXPERTS / 4 / 256), dim3(256), 0, stream>>>(part, cur, 4);
    } else {
        snn_gemm_sk<HIDDEN><<<dim3(T_TOTAL / BM, 1), dim3(128), 0, stream>>>(hs, w, cur, flags);
    }
    snn_scan_wfr<<<dim3(NCHUNK), dim3(256), 0, stream>>>(cur, out, states, flags);
}

// Round 9
// 87.990 us; speedup vs baseline: 1.1156x; 1.1156x over previous
//
#include <hip/hip_runtime.h>
#include <stdint.h>

#define HIDDEN 2048
#define EXPERTS 64
#define T_TOTAL 8192

// ================= GEMM: split-K, global_load_lds staged, 8x8 micro-tile =================
// (unchanged from R8 except: zeroes 256 flag ints for the larger NCHUNK)
#define BM 128
#define BK 32

#define GLOAD16(g, l) __builtin_amdgcn_global_load_lds(                        \
        (const __attribute__((address_space(1))) unsigned int*)(g),            \
        (__attribute__((address_space(3))) unsigned int*)(l), 16, 0, 0)
#define FENCE() asm volatile("" ::: "memory")

template <int KS>
__global__ __launch_bounds__(128, 1) void snn_gemm_sk(
        const float* __restrict__ A, const float* __restrict__ W,
        float* __restrict__ P, int* __restrict__ flags) {
    __shared__ float As[2][BM * BK];        // 2 x 16 KB
    __shared__ float Ws[2][BK * EXPERTS];   // 2 x 8 KB

    const int t    = threadIdx.x;           // 0..127
    const int lane = t & 63;
    const int wv   = t >> 6;                // 0..1
    const int rg   = t >> 3;                // 0..15 : rows rg*8..rg*8+7
    const int eg   = t & 7;                 // 0..7  : experts eg*8..eg*8+7
    const long row0 = (long)blockIdx.x * BM;
    const int  k0   = blockIdx.y * KS;
    float* Pout = P + (long)blockIdx.y * ((long)T_TOTAL * EXPERTS);

    // replaces hipMemsetAsync: scan runs after this kernel completes (stream order)
    if (blockIdx.x == 0 && blockIdx.y == 0) { flags[t] = 0; flags[t + 128] = 0; }

    // ---- staging geometry ----
    // A: 8 rounds of 128 lanes x 16B. Round p, LDS word = p*512 + wv*256 + lane*4:
    //   row = p*16 + wv*8 + (lane>>3), colblk = lane&7. Stored value is
    //   A[row][colblk ^ ((row>>3)&7)] (pre-swizzled global source; (row>>3)&7 == rg of reader).
    const int l3 = lane >> 3, l7 = lane & 7;
    const float* aSrc[8];
#pragma unroll
    for (int p = 0; p < 8; ++p) {
        const int row = p * 16 + wv * 8 + l3;
        const int cb  = l7 ^ ((row >> 3) & 7);
        aSrc[p] = &A[(row0 + row) * HIDDEN + k0 + cb * 4];
    }
    // W: 4 rounds, linear both sides.
    const float* wSrc[4];
#pragma unroll
    for (int p = 0; p < 4; ++p)
        wSrc[p] = &W[(long)(k0 + p * 8 + wv * 4 + (lane >> 4)) * EXPERTS + (lane & 15) * 4];

    auto stage = [&](int tile, int buf) {
        const int  aoff = tile * BK;
        const long woff = (long)tile * BK * EXPERTS;
#pragma unroll
        for (int p = 0; p < 8; ++p)
            GLOAD16(aSrc[p] + aoff, &As[buf][p * 512 + wv * 256]);   // +lane*16B by HW
#pragma unroll
        for (int p = 0; p < 4; ++p)
            GLOAD16(wSrc[p] + woff, &Ws[buf][p * 512 + wv * 256]);
    };

    float acc[8][8];
#pragma unroll
    for (int i = 0; i < 8; ++i)
#pragma unroll
        for (int j = 0; j < 8; ++j) acc[i][j] = 0.0f;

    stage(0, 0);

    constexpr int NTILE = KS / BK;
    int buf = 0;
    for (int tile = 0; tile < NTILE; ++tile) {
        if (tile + 1 < NTILE) {
            stage(tile + 1, buf ^ 1);
            asm volatile("s_waitcnt vmcnt(12)" ::: "memory");   // oldest 12 (current tile) landed
        } else {
            asm volatile("s_waitcnt vmcnt(0)" ::: "memory");
        }
        __builtin_amdgcn_s_barrier();
        FENCE();

        const float* ab = &As[buf][0];
        const float* wb = &Ws[buf][0];
        const int swz = rg & 7;   // == (row>>3)&7 for every row rg*8+i, i<8
#pragma unroll
        for (int q = 0; q < BK / 4; ++q) {
            const int qs = (q ^ swz) * 4;   // LDS slot holding true cols q*4..q*4+3
            float4 a4[8];
#pragma unroll
            for (int i = 0; i < 8; ++i)
                a4[i] = *reinterpret_cast<const float4*>(&ab[(rg * 8 + i) * BK + qs]);
#pragma unroll
            for (int ki = 0; ki < 4; ++ki) {   // k ascending: q outer, ki inner
                const float4 w0 = *reinterpret_cast<const float4*>(&wb[(q * 4 + ki) * EXPERTS + eg * 8]);
                const float4 w1 = *reinterpret_cast<const float4*>(&wb[(q * 4 + ki) * EXPERTS + eg * 8 + 4]);
#pragma unroll
                for (int i = 0; i < 8; ++i) {
                    const float av = (&a4[i].x)[ki];
                    acc[i][0] = fmaf(av, w0.x, acc[i][0]);
                    acc[i][1] = fmaf(av, w0.y, acc[i][1]);
                    acc[i][2] = fmaf(av, w0.z, acc[i][2]);
                    acc[i][3] = fmaf(av, w0.w, acc[i][3]);
                    acc[i][4] = fmaf(av, w1.x, acc[i][4]);
                    acc[i][5] = fmaf(av, w1.y, acc[i][5]);
                    acc[i][6] = fmaf(av, w1.z, acc[i][6]);
                    acc[i][7] = fmaf(av, w1.w, acc[i][7]);
                }
            }
        }
        FENCE();
        __builtin_amdgcn_s_barrier();   // all waves done with buf before restage
        buf ^= 1;
    }

#pragma unroll
    for (int i = 0; i < 8; ++i) {
        float* base = &Pout[(row0 + rg * 8 + i) * EXPERTS + eg * 8];
        *reinterpret_cast<float4*>(base)     = make_float4(acc[i][0], acc[i][1], acc[i][2], acc[i][3]);
        *reinterpret_cast<float4*>(base + 4) = make_float4(acc[i][4], acc[i][5], acc[i][6], acc[i][7]);
    }
}

// ========= Scan (WFR, 64 chunks x 128 steps) + fused combine + fused softmax =========
#define NCHUNK 64
#define CSTEPS (T_TOTAL / NCHUNK)   // 128
#define KITER  4
#define PF     32

// One WFR iteration over this block's chunk. curS holds DT-premultiplied currents in LDS.
// STORE: write the pre-reset membrane trajectory to smp (only needed on the final iter).
template <bool STORE>
__device__ __forceinline__ void lif_iter(const float* __restrict__ curS,
                                         float* __restrict__ smp,
                                         int e, float& mp, float& refr) {
#pragma clang fp contract(off)
    float ca[PF], cb[PF];
#pragma unroll
    for (int j = 0; j < PF; ++j) ca[j] = curS[j * EXPERTS + e];

    for (int t0 = 0; t0 < CSTEPS; t0 += 2 * PF) {
#pragma unroll
        for (int j = 0; j < PF; ++j) cb[j] = curS[(t0 + PF + j) * EXPERTS + e];
#pragma unroll
        for (int j = 0; j < PF; ++j) {
            const float term   = (refr <= 0.0f) ? ca[j] : 0.0f;
            const float mp_pre = mp * 0.9f + term;
            if constexpr (STORE) smp[(t0 + j) * EXPERTS + e] = mp_pre;
            const bool spike = mp_pre > 1.0f;
            mp = spike ? 0.0f : mp_pre;
            const float rdec = fmaxf(refr - 0.1f, 0.0f);
            refr = spike ? 1.0f : rdec;
        }
        if (t0 + 2 * PF < CSTEPS) {
#pragma unroll
            for (int j = 0; j < PF; ++j) ca[j] = curS[(t0 + 2 * PF + j) * EXPERTS + e];
        }
#pragma unroll
        for (int j = 0; j < PF; ++j) {
            const float term   = (refr <= 0.0f) ? cb[j] : 0.0f;
            const float mp_pre = mp * 0.9f + term;
            if constexpr (STORE) smp[(t0 + PF + j) * EXPERTS + e] = mp_pre;
            const bool spike = mp_pre > 1.0f;
            mp = spike ? 0.0f : mp_pre;
            const float rdec = fmaxf(refr - 0.1f, 0.0f);
            refr = spike ? 1.0f : rdec;
        }
    }
}

__global__ __launch_bounds__(256) void snn_scan_wfr(const float* __restrict__ part,
                                                    float* __restrict__ out,
                                                    float* __restrict__ states,
                                                    int* __restrict__ flags,
                                                    int nsplit) {
    __shared__ float curS[CSTEPS * EXPERTS];   // 32 KB: DT-premultiplied combined currents
    __shared__ float smp[CSTEPS * EXPERTS];    // 32 KB: final-iter pre-reset trajectory
    const int tid = threadIdx.x;
    const int w   = blockIdx.x;

    // ---- fused fixed-order split-K combine into LDS: cur = (((p0+p1)+p2)+...)*DT ----
    {
        const float4* p4 = reinterpret_cast<const float4*>(part) + (long)w * (CSTEPS * EXPERTS / 4);
        float4* c4 = reinterpret_cast<float4*>(curS);
#pragma unroll 2
        for (int i = tid; i < CSTEPS * EXPERTS / 4; i += 256) {
            float4 s = p4[i];
            for (int k = 1; k < nsplit; ++k) {
                const float4 v = p4[i + (long)k * (T_TOTAL * EXPERTS / 4)];
                s.x += v.x; s.y += v.y; s.z += v.z; s.w += v.w;
            }
            s.x *= 0.1f; s.y *= 0.1f; s.z *= 0.1f; s.w *= 0.1f;
            c4[i] = s;
        }
    }
    __syncthreads();

    if (tid < 64) {
        const int e = tid;
        for (int k = 1; k <= KITER; ++k) {
            float mp = 0.0f, refr = 0.0f;
            if (w > 0 && k > 1) {
                const int s = (k - 2) * NCHUNK + (w - 1);
                if (e == 0) {
                    while (__hip_atomic_load(&flags[s], __ATOMIC_ACQUIRE, __HIP_MEMORY_SCOPE_AGENT) == 0)
                        __builtin_amdgcn_s_sleep(8);
                }
                __threadfence();
                mp   = __hip_atomic_load(&states[s * 2 * EXPERTS + e], __ATOMIC_RELAXED, __HIP_MEMORY_SCOPE_AGENT);
                refr = __hip_atomic_load(&states[s * 2 * EXPERTS + EXPERTS + e], __ATOMIC_RELAXED, __HIP_MEMORY_SCOPE_AGENT);
            }

            if (k < KITER) lif_iter<false>(curS, smp, e, mp, refr);
            else           lif_iter<true >(curS, smp, e, mp, refr);

            if (k < KITER && w < NCHUNK - 1) {
                const int s2 = (k - 1) * NCHUNK + w;
                __hip_atomic_store(&states[s2 * 2 * EXPERTS + e], mp, __ATOMIC_RELAXED, __HIP_MEMORY_SCOPE_AGENT);
                __hip_atomic_store(&states[s2 * 2 * EXPERTS + EXPERTS + e], refr, __ATOMIC_RELAXED, __HIP_MEMORY_SCOPE_AGENT);
                __threadfence();
                if (e == 0)
                    __hip_atomic_store(&flags[s2], 1, __ATOMIC_RELEASE, __HIP_MEMORY_SCOPE_AGENT);
            }
        }
    }
    __syncthreads();

    // ---- fused routing softmax: wave wvid handles rows wvid*32 .. +31 ----
    const int lane = tid & 63;
    const int wvid = tid >> 6;
    const float em1 = expf(-1.0f);
#pragma unroll 4
    for (int r = wvid * 32; r < wvid * 32 + 32; ++r) {
        const float v = smp[r * EXPERTS + lane];
        const bool spike = v > 1.0f;
        const unsigned long long ball = __ballot(spike);
        float res;
        if (ball != 0ull) {
            const int n = __popcll(ball);
            const float denom = (float)n + (float)(EXPERTS - n) * em1;
            res = spike ? (1.0f / denom) : (em1 / denom);
        } else {
            float m = v;
#pragma unroll
            for (int off = 32; off >= 1; off >>= 1)
                m = fmaxf(m, __shfl_xor(m, off, 64));
            const float p = expf(v - m);
            float s = p;
#pragma unroll
            for (int off = 32; off >= 1; off >>= 1)
                s += __shfl_xor(s, off, 64);
            res = p / s;
        }
        out[((long)w * CSTEPS + r) * EXPERTS + lane] = res;
    }
}

// ---------------------------------------------------------------------------
extern "C" void kernel_launch(void* const* d_in, const int* in_sizes, int n_in,
                              void* d_out, int out_size, void* d_ws, size_t ws_size,
                              hipStream_t stream) {
    const float* hs = (const float*)d_in[0];   // [4,2048,2048] f32
    const float* w  = (const float*)d_in[1];   // [2048,64] f32
    float* out = (float*)d_out;                // [4,2048,64] f32

    char*  ws     = (char*)d_ws;
    int*   flags  = (int*)ws;                          // 256 ints (zeroed by gemm blk 0,0)
    float* states = (float*)(ws + 4096);               // ~96 KB used
    float* cur    = (float*)(ws + (1u << 20));         // 2 MB @ 1 MB (nsplit=1 path)
    float* part   = (float*)(ws + (4u << 20));         // up to 8 x 2 MB @ 4 MB

    const size_t slab = (size_t)T_TOTAL * EXPERTS * sizeof(float);   // 2 MB

    if (ws_size >= (4u << 20) + 8 * slab) {
        snn_gemm_sk<HIDDEN / 8><<<dim3(T_TOTAL / BM, 8), dim3(128), 0, stream>>>(hs, w, part, flags);
        snn_scan_wfr<<<dim3(NCHUNK), dim3(256), 0, stream>>>(part, out, states, flags, 8);
    } else if (ws_size >= (4u << 20) + 4 * slab) {
        snn_gemm_sk<HIDDEN / 4><<<dim3(T_TOTAL / BM, 4), dim3(128), 0, stream>>>(hs, w, part, flags);
        snn_scan_wfr<<<dim3(NCHUNK), dim3(256), 0, stream>>>(part, out, states, flags, 4);
    } else {
        snn_gemm_sk<HIDDEN><<<dim3(T_TOTAL / BM, 1), dim3(128), 0, stream>>>(hs, w, cur, flags);
        snn_scan_wfr<<<dim3(NCHUNK), dim3(256), 0, stream>>>(cur, out, states, flags, 1);
    }
}

// Round 10
// 66.366 us; speedup vs baseline: 1.4791x; 1.3258x over previous
//
#include <hip/hip_runtime.h>
#include <stdint.h>

#define HIDDEN 2048
#define EXPERTS 64
#define T_TOTAL 8192

// ================= GEMM: split-K, global_load_lds staged, 8x8 micro-tile =================
// Block: 128 thr (2 waves), BM=128 rows x 64 experts, templated BK.
// Thread: rg=t>>3 -> rows rg*8..+7, eg=t&7 -> experts eg*8..+7.
// A tile XOR-swizzled with key (row>>3)&(BK/4-1) == rg masked (R8-proven), applied on
// BOTH sides (pre-swizzled gload source + swizzled ds_read). W tile linear (2-way = free).
// nsplit=16/BK=16: LDS 24 KB -> grid 1024 = 4 blocks/CU = 8 waves/CU = 2/SIMD
// (R9 lesson: 1 wave/SIMD exposes all LDS latency).
#define BM 128

#define GLOAD16(g, l) __builtin_amdgcn_global_load_lds(                        \
        (const __attribute__((address_space(1))) unsigned int*)(g),            \
        (__attribute__((address_space(3))) unsigned int*)(l), 16, 0, 0)
#define FENCE() asm volatile("" ::: "memory")

template <int KS, int BK>
__global__ __launch_bounds__(128) void snn_gemm_sk(
        const float* __restrict__ A, const float* __restrict__ W,
        float* __restrict__ P) {
    __shared__ float As[2][BM * BK];
    __shared__ float Ws[2][BK * EXPERTS];

    constexpr int CB = BK / 4;       // 16B col-blocks per row
    constexpr int AR = BK / 4;       // A staging rounds (128 thr x 16B = 2 KB/round)
    constexpr int WR = BK / 8;       // W staging rounds
    constexpr int L  = AR + WR;      // loads in flight per stage

    const int t    = threadIdx.x;    // 0..127
    const int wv   = t >> 6;
    const int rg   = t >> 3;         // 0..15 : rows rg*8..rg*8+7
    const int eg   = t & 7;          // 0..7  : experts eg*8..eg*8+7
    const long row0 = (long)blockIdx.x * BM;
    const int  k0   = blockIdx.y * KS;
    float* Pout = P + (long)blockIdx.y * ((long)T_TOTAL * EXPERTS);

    // A staging: round p, LDS word = p*512 + wv*256 + lane*4:
    //   row = p*(512/BK) + t/CB, colblk = t&(CB-1); source col pre-swizzled by (row>>3).
    const float* aSrc[AR];
#pragma unroll
    for (int p = 0; p < AR; ++p) {
        const int row = p * (512 / BK) + t / CB;
        const int cb  = (t & (CB - 1)) ^ ((row >> 3) & (CB - 1));
        aSrc[p] = &A[(row0 + row) * HIDDEN + k0 + cb * 4];
    }
    // W staging: round p: k = p*8 + (t>>4), e4 = t&15. Linear both sides.
    const float* wSrc[WR];
#pragma unroll
    for (int p = 0; p < WR; ++p)
        wSrc[p] = &W[(long)(k0 + p * 8 + (t >> 4)) * EXPERTS + (t & 15) * 4];

    auto stage = [&](int tile, int buf) {
        const int  aoff = tile * BK;
        const long woff = (long)tile * BK * EXPERTS;
#pragma unroll
        for (int p = 0; p < AR; ++p)
            GLOAD16(aSrc[p] + aoff, &As[buf][p * 512 + wv * 256]);   // +lane*16B by HW
#pragma unroll
        for (int p = 0; p < WR; ++p)
            GLOAD16(wSrc[p] + woff, &Ws[buf][p * 512 + wv * 256]);
    };

    float acc[8][8];
#pragma unroll
    for (int i = 0; i < 8; ++i)
#pragma unroll
        for (int j = 0; j < 8; ++j) acc[i][j] = 0.0f;

    stage(0, 0);

    constexpr int NTILE = KS / BK;
    int buf = 0;
    for (int tile = 0; tile < NTILE; ++tile) {
        if (tile + 1 < NTILE) {
            stage(tile + 1, buf ^ 1);
            if constexpr (L == 6)  asm volatile("s_waitcnt vmcnt(6)" ::: "memory");
            else                   asm volatile("s_waitcnt vmcnt(12)" ::: "memory");
        } else {
            asm volatile("s_waitcnt vmcnt(0)" ::: "memory");
        }
        __builtin_amdgcn_s_barrier();
        FENCE();

        const float* ab = &As[buf][0];
        const float* wb = &Ws[buf][0];
        const int swz = rg & (CB - 1);   // == (row>>3)&(CB-1) for rows rg*8+i
#pragma unroll
        for (int q = 0; q < CB; ++q) {
            const int qs = (q ^ swz) * 4;
            float4 a4[8];
#pragma unroll
            for (int i = 0; i < 8; ++i)
                a4[i] = *reinterpret_cast<const float4*>(&ab[(rg * 8 + i) * BK + qs]);
#pragma unroll
            for (int ki = 0; ki < 4; ++ki) {   // k ascending: q outer, ki inner
                const float4 w0 = *reinterpret_cast<const float4*>(&wb[(q * 4 + ki) * EXPERTS + eg * 8]);
                const float4 w1 = *reinterpret_cast<const float4*>(&wb[(q * 4 + ki) * EXPERTS + eg * 8 + 4]);
#pragma unroll
                for (int i = 0; i < 8; ++i) {
                    const float av = (&a4[i].x)[ki];
                    acc[i][0] = fmaf(av, w0.x, acc[i][0]);
                    acc[i][1] = fmaf(av, w0.y, acc[i][1]);
                    acc[i][2] = fmaf(av, w0.z, acc[i][2]);
                    acc[i][3] = fmaf(av, w0.w, acc[i][3]);
                    acc[i][4] = fmaf(av, w1.x, acc[i][4]);
                    acc[i][5] = fmaf(av, w1.y, acc[i][5]);
                    acc[i][6] = fmaf(av, w1.z, acc[i][6]);
                    acc[i][7] = fmaf(av, w1.w, acc[i][7]);
                }
            }
        }
        FENCE();
        __builtin_amdgcn_s_barrier();   // all waves done with buf before restage
        buf ^= 1;
    }

#pragma unroll
    for (int i = 0; i < 8; ++i) {
        float* base = &Pout[(row0 + rg * 8 + i) * EXPERTS + eg * 8];
        *reinterpret_cast<float4*>(base)     = make_float4(acc[i][0], acc[i][1], acc[i][2], acc[i][3]);
        *reinterpret_cast<float4*>(base + 4) = make_float4(acc[i][4], acc[i][5], acc[i][6], acc[i][7]);
    }
}

// ---- fixed-order split-K combine (template-unrolled: all loads issued in parallel) ----
template <int NS>
__global__ __launch_bounds__(256) void snn_combine(const float* __restrict__ P,
                                                   float* __restrict__ cur) {
    const long i = (long)blockIdx.x * 256 + threadIdx.x;   // float4 index
    const float4* p = reinterpret_cast<const float4*>(P);
    float4 s = p[i];
#pragma unroll
    for (int k = 1; k < NS; ++k) {
        const float4 v = p[i + (long)k * (T_TOTAL * EXPERTS / 4)];
        s.x += v.x; s.y += v.y; s.z += v.z; s.w += v.w;
    }
    reinterpret_cast<float4*>(cur)[i] = s;
}

// ========= Scan: zero-sync overlap (warm-up 256 steps) + fused softmax =========
// Block w computes steps [w*128-256, w*128+128) from zero state; 0.9^256 forgetting
// makes the output-window state exact (whp bitwise). No flags/states/fences.
#define NCHUNK 64
#define CSTEPS (T_TOTAL / NCHUNK)   // 128
#define WARM   256

// One 32-step chunk from register buffer. STORE: write pre-reset mp to smp.
template <bool STORE>
__device__ __forceinline__ void lif_chunk(const float (&cbuf)[32], float* __restrict__ smp,
                                          int orow, int e, float& mp, float& refr) {
#pragma clang fp contract(off)
#pragma unroll
    for (int j = 0; j < 32; ++j) {
        const float term   = (refr <= 0.0f) ? cbuf[j] : 0.0f;
        const float mp_pre = mp * 0.9f + term;
        if constexpr (STORE) smp[(orow + j) * EXPERTS + e] = mp_pre;
        const bool spike = mp_pre > 1.0f;
        mp = spike ? 0.0f : mp_pre;
        const float rdec = fmaxf(refr - 0.1f, 0.0f);
        refr = spike ? 1.0f : rdec;
    }
}

__global__ __launch_bounds__(256) void snn_scan_ov(const float* __restrict__ cur,
                                                   float* __restrict__ out) {
    __shared__ float smp[CSTEPS * EXPERTS];   // 32 KB: output-window pre-reset trajectory
    const int tid = threadIdx.x;
    const int w   = blockIdx.x;

    if (tid < 64) {
        const int e     = tid;
        const int t0abs = w * CSTEPS;
        const int s0    = (t0abs >= WARM) ? (t0abs - WARM) : 0;
        const int nwarm = t0abs - s0;              // 0, 128 or 256 (mult of 32)
        const int cwarm = nwarm >> 5;
        const int nc    = cwarm + (CSTEPS >> 5);   // 4, 8 or 12 (even)
        const float* cb = cur + (long)s0 * EXPERTS + e;

        float mp = 0.0f, refr = 0.0f;
        float bufA[32], bufB[32];
#pragma unroll
        for (int j = 0; j < 32; ++j) bufA[j] = cb[j * EXPERTS] * 0.1f;

        for (int c2 = 0; c2 < nc; c2 += 2) {
            // prefetch chunk c2+1 into B
            if (c2 + 1 < nc)
#pragma unroll
                for (int j = 0; j < 32; ++j) bufB[j] = cb[((c2 + 1) * 32 + j) * EXPERTS] * 0.1f;
            // compute chunk c2 from A
            if (c2 >= cwarm) lif_chunk<true >(bufA, smp, c2 * 32 - nwarm, e, mp, refr);
            else             lif_chunk<false>(bufA, smp, 0, e, mp, refr);
            // prefetch chunk c2+2 into A
            if (c2 + 2 < nc)
#pragma unroll
                for (int j = 0; j < 32; ++j) bufA[j] = cb[((c2 + 2) * 32 + j) * EXPERTS] * 0.1f;
            // compute chunk c2+1 from B  (nc even -> always valid)
            if (c2 + 1 >= cwarm) lif_chunk<true >(bufB, smp, (c2 + 1) * 32 - nwarm, e, mp, refr);
            else                 lif_chunk<false>(bufB, smp, 0, e, mp, refr);
        }
    }
    __syncthreads();

    // ---- fused routing softmax: wave wvid handles rows wvid*32 .. +31 ----
    const int lane = tid & 63;
    const int wvid = tid >> 6;
    const float em1 = expf(-1.0f);
#pragma unroll 4
    for (int r = wvid * 32; r < wvid * 32 + 32; ++r) {
        const float v = smp[r * EXPERTS + lane];
        const bool spike = v > 1.0f;
        const unsigned long long ball = __ballot(spike);
        float res;
        if (ball != 0ull) {
            const int n = __popcll(ball);
            const float denom = (float)n + (float)(EXPERTS - n) * em1;
            res = spike ? (1.0f / denom) : (em1 / denom);
        } else {
            float m = v;
#pragma unroll
            for (int off = 32; off >= 1; off >>= 1)
                m = fmaxf(m, __shfl_xor(m, off, 64));
            const float p = expf(v - m);
            float s = p;
#pragma unroll
            for (int off = 32; off >= 1; off >>= 1)
                s += __shfl_xor(s, off, 64);
            res = p / s;
        }
        out[((long)w * CSTEPS + r) * EXPERTS + lane] = res;
    }
}

// ---------------------------------------------------------------------------
extern "C" void kernel_launch(void* const* d_in, const int* in_sizes, int n_in,
                              void* d_out, int out_size, void* d_ws, size_t ws_size,
                              hipStream_t stream) {
    const float* hs = (const float*)d_in[0];   // [4,2048,2048] f32
    const float* w  = (const float*)d_in[1];   // [2048,64] f32
    float* out = (float*)d_out;                // [4,2048,64] f32

    char*  ws   = (char*)d_ws;
    float* cur  = (float*)(ws + (1u << 20));   // 2 MB @ 1 MB
    float* part = (float*)(ws + (4u << 20));   // up to 16 x 2 MB @ 4 MB

    const size_t slab = (size_t)T_TOTAL * EXPERTS * sizeof(float);   // 2 MB

    if (ws_size >= (4u << 20) + 16 * slab) {
        snn_gemm_sk<HIDDEN / 16, 16><<<dim3(T_TOTAL / BM, 16), dim3(128), 0, stream>>>(hs, w, part);
        snn_combine<16><<<dim3(T_TOTAL * EXPERTS / 4 / 256), dim3(256), 0, stream>>>(part, cur);
    } else if (ws_size >= (4u << 20) + 8 * slab) {
        snn_gemm_sk<HIDDEN / 8, 32><<<dim3(T_TOTAL / BM, 8), dim3(128), 0, stream>>>(hs, w, part);
        snn_combine<8><<<dim3(T_TOTAL * EXPERTS / 4 / 256), dim3(256), 0, stream>>>(part, cur);
    } else {
        snn_gemm_sk<HIDDEN, 32><<<dim3(T_TOTAL / BM, 1), dim3(128), 0, stream>>>(hs, w, cur);
    }
    snn_scan_ov<<<dim3(NCHUNK), dim3(256), 0, stream>>>(cur, out);
}